// Round 4
// baseline (287.657 us; speedup 1.0000x reference)
//
#include <hip/hip_runtime.h>
#include <hip/hip_bf16.h>

// Problem constants
#define BATCH   4096
#define SDIM    512
#define ADIM    64
#define IDIM    577           // 512 + 64 + 1
#define KP2     640           // IDIM padded to 10*64
#define NKT2    10            // K-tiles of 64
#define HDIM    2048
#define ZDIM    8192          // 4*HDIM

typedef __attribute__((ext_vector_type(8))) __bf16 bf16x8;
typedef __attribute__((ext_vector_type(4))) float  accx4;

// ---------------------------------------------------------------------------
// Fused setup kernel. Role by flat blockIdx (all independent):
//   [0,2560)     transpose Wx [577,8192]f32 -> wxt [8192][640]bf16
//   [2560,3072)  zh partials: zh_w[ky][n] = sum_{k in ky*128..+128} h*Wh
//   [3072,7168)  prep xb rows: bf16 [s|a|r|0pad] (4096 x 640)
//   [7168,7296)  transpose Wa [2048,64]f32 -> waT [64][2048]bf16
// ---------------------------------------------------------------------------
__global__ __launch_bounds__(256) void setup_kernel(
    const float* __restrict__ s, const float* __restrict__ a_prev,
    const float* __restrict__ r_prev, const float* __restrict__ h,
    const float* __restrict__ wx, const float* __restrict__ wh,
    const float* __restrict__ wa,
    __hip_bfloat16* __restrict__ xb, __hip_bfloat16* __restrict__ wxt,
    __hip_bfloat16* __restrict__ waT, float* __restrict__ zh_w)
{
    __shared__ float stile[64 * 33];
    const int bid = blockIdx.x;
    const int t = threadIdx.x;

    if (bid < 2560) {                       // ---- transpose Wx (64k x 32n)
        const int kt2 = bid >> 8;           // 0..9
        const int nt  = bid & 255;          // 0..255
        const int c  = t & 31, r0 = t >> 5;
#pragma unroll
        for (int i = 0; i < 8; ++i) {
            int r = r0 + i * 8;             // k within tile
            int k = kt2 * 64 + r;
            stile[r * 33 + c] =
                (k < IDIM) ? wx[(size_t)k * ZDIM + nt * 32 + c] : 0.0f;
        }
        __syncthreads();
        const int nr = t >> 3, ch = t & 7;
        bf16x8 w8;
#pragma unroll
        for (int j = 0; j < 8; ++j)
            w8[j] = (__bf16)stile[(ch * 8 + j) * 33 + nr];
        *(bf16x8*)(wxt + (size_t)(nt * 32 + nr) * KP2 + kt2 * 64 + ch * 8) = w8;
    } else if (bid < 3072) {                // ---- zh partials (16 k-splits)
        const int zb = bid - 2560;
        const int nb = zb & 31, ky = zb >> 5;       // nb 0..31, ky 0..15
        const int n  = nb * 256 + t;
        const float* hp  = h + ky * 128;
        const float* whp = wh + (size_t)ky * 128 * ZDIM + n;
        float p = 0.0f;
#pragma unroll 32
        for (int kk = 0; kk < 128; ++kk)
            p = fmaf(hp[kk], whp[(size_t)kk * ZDIM], p);
        zh_w[ky * ZDIM + n] = p;
    } else if (bid < 7168) {                // ---- prep xb row
        const int row = bid - 3072;
        const float* srow = s + (size_t)row * SDIM;
        const float* arow = a_prev + (size_t)row * ADIM;
        __hip_bfloat16* xrow = xb + (size_t)row * KP2;
        for (int c = t; c < KP2; c += 256) {
            float v;
            if (c < SDIM)        v = srow[c];
            else if (c < 576)    v = arow[c - SDIM];
            else if (c == 576)   v = r_prev[row];
            else                 v = 0.0f;
            xrow[c] = __float2bfloat16(v);
        }
    } else {                                // ---- transpose Wa (32k x 32a)
        const int wb = bid - 7168;
        const int kt = wb >> 1, at = wb & 1;
        const int c  = t & 31, r0 = t >> 5;
#pragma unroll
        for (int i = 0; i < 4; ++i) {
            int r = r0 + i * 8;             // k within tile
            stile[r * 33 + c] = wa[(size_t)(kt * 32 + r) * ADIM + at * 32 + c];
        }
        __syncthreads();
#pragma unroll
        for (int i = 0; i < 4; ++i) {
            int r = r0 + i * 8;             // action within tile
            waT[(size_t)(at * 32 + r) * HDIM + kt * 32 + c] =
                __float2bfloat16(stile[c * 33 + r]);
        }
    }
}

// ---------------------------------------------------------------------------
// Main bf16 MFMA GEMM + fused LSTM epilogue — BARRIER-FREE, NO LDS.
// Block 128 rows x 64 h-units (=> 256 z-cols over 4 gates). 4 waves 2x2:
// wave = 64 rows x 32 hu. Fragments loaded DIRECTLY from global (pattern
// proven correct+fast by head_kernel): per lane a 16B k-chunk; per load
// instr 16 rows x 64B segments, L2/L3-resident (xb+wxt = 15.7 MB < L3).
// A-frags reused in registers across 8 z-tiles. Compiler free to pipeline
// loads across the fully-unrollable 10-iteration K-loop (no vmcnt(0) drain).
// ---------------------------------------------------------------------------
__device__ __forceinline__ float sigmoid_f(float x) {
    return 1.0f / (1.0f + __expf(-x));
}
__device__ __forceinline__ float tanh_f(float x) {
    return 1.0f - 2.0f / (1.0f + __expf(2.0f * x));
}

__global__ __launch_bounds__(256, 2) void lstm_gemm(
    const __hip_bfloat16* __restrict__ xb,   // [4096][640] bf16
    const __hip_bfloat16* __restrict__ wxt,  // [8192][640] bf16 (n-major)
    const float* __restrict__ zh_w,          // [16][8192] k-split partials
    const float* __restrict__ bh,            // [8192]
    const float* __restrict__ cvec,          // [2048]
    __hip_bfloat16* __restrict__ hout)       // [4096][2048] bf16
{
    const int t    = threadIdx.x;
    const int lane = t & 63;
    const int wid  = t >> 6;
    const int m0   = blockIdx.x * 128;       // x fastest: co-resident blocks
    const int n0   = blockIdx.y * 64;        //   share A-rows (L2 locality)
    const int wm   = wid >> 1, wn = wid & 1;
    const int fl15 = lane & 15;
    const int fhi  = lane >> 4;              // 0..3 k-chunk

    accx4 acc[4][2][4] = {};                 // [gate][hu-tile][rowtile]

    const __bf16* arow = (const __bf16*)xb +
        (size_t)(m0 + wm * 64 + fl15) * KP2 + fhi * 8;
    const __bf16* brow = (const __bf16*)wxt +
        (size_t)(n0 + wn * 32 + fl15) * KP2 + fhi * 8;

#pragma unroll 2
    for (int ks = 0; ks < 2 * NKT2; ++ks) {  // 20 half-tiles of k=32
        const int ko = ks * 32;
        bf16x8 af[4];
#pragma unroll
        for (int rt = 0; rt < 4; ++rt)
            af[rt] = *(const bf16x8*)(arow + (size_t)rt * 16 * KP2 + ko);
#pragma unroll
        for (int g = 0; g < 4; ++g) {
#pragma unroll
            for (int ht = 0; ht < 2; ++ht) {
                bf16x8 bf = *(const bf16x8*)(brow +
                    (size_t)(g * HDIM + ht * 16) * KP2 + ko);
#pragma unroll
                for (int rt = 0; rt < 4; ++rt)
                    acc[g][ht][rt] = __builtin_amdgcn_mfma_f32_16x16x32_bf16(
                        af[rt], bf, acc[g][ht][rt], 0, 0, 0);
            }
        }
    }

    // Epilogue. C/D layout: col=lane&15, row=(lane>>4)*4+reg (m89/m91).
#pragma unroll
    for (int ht = 0; ht < 2; ++ht) {
        const int colg = n0 + wn * 32 + ht * 16 + fl15;   // h-unit index
        float zsum[4];
#pragma unroll
        for (int g = 0; g < 4; ++g) {
            float z = bh[g * HDIM + colg];
#pragma unroll
            for (int j = 0; j < 16; ++j)
                z += zh_w[j * ZDIM + g * HDIM + colg];
            zsum[g] = z;
        }
        const float cv = cvec[colg];
#pragma unroll
        for (int rt = 0; rt < 4; ++rt) {
#pragma unroll
            for (int r = 0; r < 4; ++r) {
                const int row = m0 + wm * 64 + rt * 16 + (fhi << 2) + r;
                const float zi = acc[0][ht][rt][r] + zsum[0];
                const float zf = acc[1][ht][rt][r] + zsum[1];
                const float zg = acc[2][ht][rt][r] + zsum[2];
                const float zo = acc[3][ht][rt][r] + zsum[3];
                const float cn = sigmoid_f(zf) * cv
                               + sigmoid_f(zi) * tanh_f(zg);
                const float hn = sigmoid_f(zo) * tanh_f(cn);
                hout[(size_t)row * HDIM + colg] = __float2bfloat16(hn);
            }
        }
    }
}

// ---------------------------------------------------------------------------
// Policy+value head: logits = hnew@Wa + ba (MFMA, K split over 2 wave-groups,
// dual accumulators), fused softmax; v = hnew@Wv + bv (fp32 Wv).
// 512 threads: wave = (kh = wid>>2, action-tile = wid&3). Block = 16 rows.
// ---------------------------------------------------------------------------
__global__ __launch_bounds__(512) void head_kernel(
    const __hip_bfloat16* __restrict__ hnew,  // [4096][2048] bf16
    const __hip_bfloat16* __restrict__ waT,   // [64][2048] bf16
    const float* __restrict__ wv,             // [2048] f32
    const float* __restrict__ ba, const float* __restrict__ bv,
    float* __restrict__ probs, float* __restrict__ vout)
{
    __shared__ float lg[2][16][68];
    __shared__ float vpart[2][16];
    const int t    = threadIdx.x;
    const int lane = t & 63;
    const int wid  = t >> 6;           // 0..7
    const int kh   = wid >> 2;         // k half
    const int wid2 = wid & 3;          // action tile
    const int r0   = blockIdx.x * 16;
    const int fl15 = lane & 15, fhi = lane >> 4;

    const __bf16* arow = (const __bf16*)hnew +
        (size_t)(r0 + fl15) * HDIM + kh * 1024 + fhi * 8;
    const __bf16* brow = (const __bf16*)waT +
        (size_t)(wid2 * 16 + fl15) * HDIM + kh * 1024 + fhi * 8;
    const float* wvp = wv + kh * 1024 + fhi * 8;
    const bool do_v = (wid2 == 0);

    accx4 acc0 = {}, acc1 = {};
    float vacc = 0.0f;
#pragma unroll 4
    for (int kk = 0; kk < 1024; kk += 64) {
        bf16x8 a0 = *(const bf16x8*)(arow + kk);
        bf16x8 b0 = *(const bf16x8*)(brow + kk);
        bf16x8 a1 = *(const bf16x8*)(arow + kk + 32);
        bf16x8 b1 = *(const bf16x8*)(brow + kk + 32);
        acc0 = __builtin_amdgcn_mfma_f32_16x16x32_bf16(a0, b0, acc0, 0, 0, 0);
        acc1 = __builtin_amdgcn_mfma_f32_16x16x32_bf16(a1, b1, acc1, 0, 0, 0);
        if (do_v) {
#pragma unroll
            for (int j = 0; j < 8; ++j) {
                vacc = fmaf((float)a0[j], wvp[kk + j], vacc);
                vacc = fmaf((float)a1[j], wvp[kk + 32 + j], vacc);
            }
        }
    }
    // C/D layout: col(action-in-tile)=lane&15, row=(lane>>4)*4+reg
#pragma unroll
    for (int r = 0; r < 4; ++r)
        lg[kh][fhi * 4 + r][wid2 * 16 + fl15] = acc0[r] + acc1[r];
    if (do_v) {
        vacc += __shfl_xor(vacc, 16);
        vacc += __shfl_xor(vacc, 32);
        if (lane < 16) vpart[kh][lane] = vacc;
    }
    __syncthreads();

    // softmax: 8 waves x 2 rows; lane = action (wave width 64 = ADIM)
    const float bav = ba[lane];
#pragma unroll
    for (int i = 0; i < 2; ++i) {
        const int row = wid * 2 + i;
        const float logit = lg[0][row][lane] + lg[1][row][lane] + bav;
        float m = logit;
#pragma unroll
        for (int mask = 32; mask >= 1; mask >>= 1)
            m = fmaxf(m, __shfl_xor(m, mask));
        const float e = __expf(logit - m);
        float ssum = e;
#pragma unroll
        for (int mask = 32; mask >= 1; mask >>= 1)
            ssum += __shfl_xor(ssum, mask);
        probs[(size_t)(r0 + row) * 64 + lane] = e / ssum;
    }
    if (t < 16) vout[r0 + t] = vpart[0][t] + vpart[1][t] + bv[0];
}

// ---------------------------------------------------------------------------
extern "C" void kernel_launch(void* const* d_in, const int* in_sizes, int n_in,
                              void* d_out, int out_size, void* d_ws,
                              size_t ws_size, hipStream_t stream)
{
    const float* s      = (const float*)d_in[0];
    const float* a_prev = (const float*)d_in[1];
    const float* r_prev = (const float*)d_in[2];
    const float* h      = (const float*)d_in[3];
    const float* c      = (const float*)d_in[4];
    const float* Wx     = (const float*)d_in[5];
    const float* Wh     = (const float*)d_in[6];
    const float* bh     = (const float*)d_in[7];
    const float* Wa     = (const float*)d_in[8];
    const float* ba     = (const float*)d_in[9];
    const float* Wv     = (const float*)d_in[10];
    const float* bv     = (const float*)d_in[11];

    float* out   = (float*)d_out;
    float* probs = out;                        // [4096*64]
    float* vout  = out + (size_t)BATCH * ADIM; // [4096]

    // Workspace layout (16B-aligned)
    char* ws = (char*)d_ws;
    __hip_bfloat16* xb   = (__hip_bfloat16*)ws;                 //  5,242,880
    __hip_bfloat16* wxt  = (__hip_bfloat16*)(ws + 5242880);     // 10,485,760
    __hip_bfloat16* waT  = (__hip_bfloat16*)(ws + 15728640);    //    262,144
    float* zh_w          = (float*)(ws + 15990784);             //    524,288
    __hip_bfloat16* hnew = (__hip_bfloat16*)(ws + 16515072);    // 16,777,216
    // total 33,292,288 bytes

    setup_kernel<<<7296, 256, 0, stream>>>(
        s, a_prev, r_prev, h, Wx, Wh, Wa, xb, wxt, waT, zh_w);
    lstm_gemm<<<dim3(BATCH / 128, HDIM / 64), 256, 0, stream>>>(
        xb, wxt, zh_w, bh, c, hnew);
    head_kernel<<<BATCH / 16, 512, 0, stream>>>(
        hnew, waT, Wv, ba, bv, probs, vout);
}

// Round 5
// 231.690 us; speedup vs baseline: 1.2416x; 1.2416x over previous
//
#include <hip/hip_runtime.h>
#include <hip/hip_bf16.h>

// Problem constants
#define BATCH   4096
#define SDIM    512
#define ADIM    64
#define IDIM    577           // 512 + 64 + 1
#define KP2     640           // IDIM padded to 10*64
#define NKT2    10            // K-tiles of 64
#define HDIM    2048
#define ZDIM    8192          // 4*HDIM
#define BUFE    (128 * 64)    // LDS elems per buffer

typedef __attribute__((ext_vector_type(8))) __bf16 bf16x8;
typedef __attribute__((ext_vector_type(4))) float  accx4;

// ---------------------------------------------------------------------------
// Fused setup kernel. Role by flat blockIdx (all independent):
//   [0,2560)     transpose Wx [577,8192]f32 -> wxt [8192][640]bf16
//   [2560,2816)  zh partials: zh_w[ky][n] = sum_{k in ky*256..+256} h*Wh
//   [2816,6912)  prep xb rows: bf16 [s|a|r|0pad] (4096 x 640)
//   [6912,7040)  transpose Wa [2048,64]f32 -> waT [64][2048]bf16
// ---------------------------------------------------------------------------
__global__ __launch_bounds__(256) void setup_kernel(
    const float* __restrict__ s, const float* __restrict__ a_prev,
    const float* __restrict__ r_prev, const float* __restrict__ h,
    const float* __restrict__ wx, const float* __restrict__ wh,
    const float* __restrict__ wa,
    __hip_bfloat16* __restrict__ xb, __hip_bfloat16* __restrict__ wxt,
    __hip_bfloat16* __restrict__ waT, float* __restrict__ zh_w)
{
    __shared__ float stile[64 * 33];
    const int bid = blockIdx.x;
    const int t = threadIdx.x;

    if (bid < 2560) {                       // ---- transpose Wx (64k x 32n)
        const int kt2 = bid >> 8;           // 0..9
        const int nt  = bid & 255;          // 0..255
        const int c  = t & 31, r0 = t >> 5;
#pragma unroll
        for (int i = 0; i < 8; ++i) {
            int r = r0 + i * 8;             // k within tile
            int k = kt2 * 64 + r;
            stile[r * 33 + c] =
                (k < IDIM) ? wx[(size_t)k * ZDIM + nt * 32 + c] : 0.0f;
        }
        __syncthreads();
        const int nr = t >> 3, ch = t & 7;
        bf16x8 w8;
#pragma unroll
        for (int j = 0; j < 8; ++j)
            w8[j] = (__bf16)stile[(ch * 8 + j) * 33 + nr];
        *(bf16x8*)(wxt + (size_t)(nt * 32 + nr) * KP2 + kt2 * 64 + ch * 8) = w8;
    } else if (bid < 2816) {                // ---- zh partials (8 k-splits)
        const int zb = bid - 2560;
        const int nb = zb & 31, ky = zb >> 5;       // nb 0..31, ky 0..7
        const int n  = nb * 256 + t;
        const float* hp  = h + ky * 256;
        const float* whp = wh + (size_t)ky * 256 * ZDIM + n;
        float p = 0.0f;
#pragma unroll 16
        for (int kk = 0; kk < 256; ++kk)
            p = fmaf(hp[kk], whp[(size_t)kk * ZDIM], p);
        zh_w[ky * ZDIM + n] = p;
    } else if (bid < 6912) {                // ---- prep xb row
        const int row = bid - 2816;
        const float* srow = s + (size_t)row * SDIM;
        const float* arow = a_prev + (size_t)row * ADIM;
        __hip_bfloat16* xrow = xb + (size_t)row * KP2;
        for (int c = t; c < KP2; c += 256) {
            float v;
            if (c < SDIM)        v = srow[c];
            else if (c < 576)    v = arow[c - SDIM];
            else if (c == 576)   v = r_prev[row];
            else                 v = 0.0f;
            xrow[c] = __float2bfloat16(v);
        }
    } else {                                // ---- transpose Wa (32k x 32a)
        const int wb = bid - 6912;
        const int kt = wb >> 1, at = wb & 1;
        const int c  = t & 31, r0 = t >> 5;
#pragma unroll
        for (int i = 0; i < 4; ++i) {
            int r = r0 + i * 8;             // k within tile
            stile[r * 33 + c] = wa[(size_t)(kt * 32 + r) * ADIM + at * 32 + c];
        }
        __syncthreads();
#pragma unroll
        for (int i = 0; i < 4; ++i) {
            int r = r0 + i * 8;             // action within tile
            waT[(size_t)(at * 32 + r) * HDIM + kt * 32 + c] =
                __float2bfloat16(stile[c * 33 + r]);
        }
    }
}

// ---------------------------------------------------------------------------
// Main bf16 MFMA GEMM + fused LSTM epilogue — DOUBLE-BUFFERED LDS.
// Block tile: 128 rows x 32 h-units (128 z-cols over 4 gates), BK=64.
// Loads for tile kt+1 are issued BEFORE computing tile kt, so the
// vmcnt(0) drain at each barrier waits on loads that already had a full
// compute phase in flight (vs R3 where latency was fully exposed).
// XOR-swizzled 16B chunks: stored slot = chunk ^ (row&7) — conflict-free
// for both staging and fragment reads (verified R3: SQ_LDS_BANK_CONFLICT=0).
// ---------------------------------------------------------------------------
__device__ __forceinline__ float sigmoid_f(float x) {
    return 1.0f / (1.0f + __expf(-x));
}
__device__ __forceinline__ float tanh_f(float x) {
    return 1.0f - 2.0f / (1.0f + __expf(2.0f * x));
}

__global__ __launch_bounds__(256, 2) void lstm_gemm(
    const __hip_bfloat16* __restrict__ xb,   // [4096][640] bf16
    const __hip_bfloat16* __restrict__ wxt,  // [8192][640] bf16 (n-major)
    const float* __restrict__ zh_w,          // [8][8192] k-split partials
    const float* __restrict__ bh,            // [8192]
    const float* __restrict__ cvec,          // [2048]
    __hip_bfloat16* __restrict__ hout)       // [4096][2048] bf16
{
    __shared__ __bf16 smA[2 * BUFE];   // 32KB  [buf][row][k-chunk swizzled]
    __shared__ __bf16 smB[2 * BUFE];   // 32KB  [buf][zcol][k-chunk swizzled]
    const int t    = threadIdx.x;
    const int lane = t & 63;
    const int wid  = t >> 6;
    const int m0   = blockIdx.x * 128;
    const int n0   = blockIdx.y * 32;
    const int wm   = wid >> 1, wn = wid & 1;
    const int fl15 = lane & 15;
    const int fhi  = lane >> 4;        // 0..3

    accx4 acc[4][4] = {};              // [gate][rowtile]

    // ---- precomputed staging addresses (loop-invariant) ----
    const int srow = lane >> 3;        // 0..7
    const int slot = lane & 7;
    const int cch  = slot ^ srow;      // swizzled chunk, same for all i
    const __bf16* gA[4]; const __bf16* gB[4];
    __bf16* lA[4]; __bf16* lB[4];
#pragma unroll
    for (int i = 0; i < 4; ++i) {
        const int r = wid * 32 + i * 8 + srow;               // 0..127
        gA[i] = (const __bf16*)xb + (size_t)(m0 + r) * KP2 + cch * 8;
        const int g = r >> 5, nn = r & 31;
        gB[i] = (const __bf16*)wxt +
                (size_t)(g * HDIM + n0 + nn) * KP2 + cch * 8;
        lA[i] = smA + (wid * 32 + i * 8) * 64;               // wave-uniform
        lB[i] = smB + (wid * 32 + i * 8) * 64;
    }

    auto stage = [&](int tile, int p) {
        const int ko = tile * 64;
        const int po = p * BUFE;
#pragma unroll
        for (int i = 0; i < 4; ++i) {
            __builtin_amdgcn_global_load_lds(
                (const __attribute__((address_space(1))) void*)(gA[i] + ko),
                (__attribute__((address_space(3))) void*)(lA[i] + po),
                16, 0, 0);
            __builtin_amdgcn_global_load_lds(
                (const __attribute__((address_space(1))) void*)(gB[i] + ko),
                (__attribute__((address_space(3))) void*)(lB[i] + po),
                16, 0, 0);
        }
    };

    auto compute = [&](int p) {
        const int po = p * BUFE;
#pragma unroll
        for (int hf = 0; hf < 2; ++hf) {
            const int sl = ((hf * 4 + fhi) ^ slot) * 8;      // de-swizzle
            bf16x8 af[4], bfr[4];
#pragma unroll
            for (int rt = 0; rt < 4; ++rt)
                af[rt] = *(const bf16x8*)(smA + po +
                    (wm * 64 + rt * 16 + fl15) * 64 + sl);
#pragma unroll
            for (int g = 0; g < 4; ++g)
                bfr[g] = *(const bf16x8*)(smB + po +
                    (g * 32 + wn * 16 + fl15) * 64 + sl);
#pragma unroll
            for (int g = 0; g < 4; ++g)
#pragma unroll
                for (int rt = 0; rt < 4; ++rt)
                    acc[g][rt] = __builtin_amdgcn_mfma_f32_16x16x32_bf16(
                        af[rt], bfr[g], acc[g][rt], 0, 0, 0);
        }
    };

    stage(0, 0);
    __syncthreads();                   // tile 0 landed
#pragma unroll
    for (int kt = 0; kt < NKT2 - 1; ++kt) {
        stage(kt + 1, (kt + 1) & 1);   // issue next tile FIRST
        compute(kt & 1);               // overlap latency with MFMAs
        __syncthreads();
    }
    compute((NKT2 - 1) & 1);           // last tile, no barrier needed

    // Epilogue. C/D layout: col=lane&15, row=(lane>>4)*4+reg (m89/m91).
    const int colg = n0 + wn * 16 + fl15;        // h-unit index
    float zsum[4];
#pragma unroll
    for (int g = 0; g < 4; ++g) {
        float z = bh[g * HDIM + colg];
#pragma unroll
        for (int j = 0; j < 8; ++j)
            z += zh_w[j * ZDIM + g * HDIM + colg];
        zsum[g] = z;
    }
    const float cv = cvec[colg];
#pragma unroll
    for (int rt = 0; rt < 4; ++rt) {
#pragma unroll
        for (int r = 0; r < 4; ++r) {
            const int row = m0 + wm * 64 + rt * 16 + (fhi << 2) + r;
            const float zi = acc[0][rt][r] + zsum[0];
            const float zf = acc[1][rt][r] + zsum[1];
            const float zg = acc[2][rt][r] + zsum[2];
            const float zo = acc[3][rt][r] + zsum[3];
            const float cn = sigmoid_f(zf) * cv + sigmoid_f(zi) * tanh_f(zg);
            const float hn = sigmoid_f(zo) * tanh_f(cn);
            hout[(size_t)row * HDIM + colg] = __float2bfloat16(hn);
        }
    }
}

// ---------------------------------------------------------------------------
// Policy+value head: logits = hnew@Wa + ba (MFMA, K split over 2 wave-groups,
// dual accumulators), fused softmax; v = hnew@Wv + bv (fp32 Wv).
// 512 threads: wave = (kh = wid>>2, action-tile = wid&3). Block = 16 rows.
// ---------------------------------------------------------------------------
__global__ __launch_bounds__(512) void head_kernel(
    const __hip_bfloat16* __restrict__ hnew,  // [4096][2048] bf16
    const __hip_bfloat16* __restrict__ waT,   // [64][2048] bf16
    const float* __restrict__ wv,             // [2048] f32
    const float* __restrict__ ba, const float* __restrict__ bv,
    float* __restrict__ probs, float* __restrict__ vout)
{
    __shared__ float lg[2][16][68];
    __shared__ float vpart[2][16];
    const int t    = threadIdx.x;
    const int lane = t & 63;
    const int wid  = t >> 6;           // 0..7
    const int kh   = wid >> 2;         // k half
    const int wid2 = wid & 3;          // action tile
    const int r0   = blockIdx.x * 16;
    const int fl15 = lane & 15, fhi = lane >> 4;

    const __bf16* arow = (const __bf16*)hnew +
        (size_t)(r0 + fl15) * HDIM + kh * 1024 + fhi * 8;
    const __bf16* brow = (const __bf16*)waT +
        (size_t)(wid2 * 16 + fl15) * HDIM + kh * 1024 + fhi * 8;
    const float* wvp = wv + kh * 1024 + fhi * 8;
    const bool do_v = (wid2 == 0);

    accx4 acc0 = {}, acc1 = {};
    float vacc = 0.0f;
#pragma unroll 4
    for (int kk = 0; kk < 1024; kk += 64) {
        bf16x8 a0 = *(const bf16x8*)(arow + kk);
        bf16x8 b0 = *(const bf16x8*)(brow + kk);
        bf16x8 a1 = *(const bf16x8*)(arow + kk + 32);
        bf16x8 b1 = *(const bf16x8*)(brow + kk + 32);
        acc0 = __builtin_amdgcn_mfma_f32_16x16x32_bf16(a0, b0, acc0, 0, 0, 0);
        acc1 = __builtin_amdgcn_mfma_f32_16x16x32_bf16(a1, b1, acc1, 0, 0, 0);
        if (do_v) {
#pragma unroll
            for (int j = 0; j < 8; ++j) {
                vacc = fmaf((float)a0[j], wvp[kk + j], vacc);
                vacc = fmaf((float)a1[j], wvp[kk + 32 + j], vacc);
            }
        }
    }
    // C/D layout: col(action-in-tile)=lane&15, row=(lane>>4)*4+reg
#pragma unroll
    for (int r = 0; r < 4; ++r)
        lg[kh][fhi * 4 + r][wid2 * 16 + fl15] = acc0[r] + acc1[r];
    if (do_v) {
        vacc += __shfl_xor(vacc, 16);
        vacc += __shfl_xor(vacc, 32);
        if (lane < 16) vpart[kh][lane] = vacc;
    }
    __syncthreads();

    // softmax: 8 waves x 2 rows; lane = action (wave width 64 = ADIM)
    const float bav = ba[lane];
#pragma unroll
    for (int i = 0; i < 2; ++i) {
        const int row = wid * 2 + i;
        const float logit = lg[0][row][lane] + lg[1][row][lane] + bav;
        float m = logit;
#pragma unroll
        for (int mask = 32; mask >= 1; mask >>= 1)
            m = fmaxf(m, __shfl_xor(m, mask));
        const float e = __expf(logit - m);
        float ssum = e;
#pragma unroll
        for (int mask = 32; mask >= 1; mask >>= 1)
            ssum += __shfl_xor(ssum, mask);
        probs[(size_t)(r0 + row) * 64 + lane] = e / ssum;
    }
    if (t < 16) vout[r0 + t] = vpart[0][t] + vpart[1][t] + bv[0];
}

// ---------------------------------------------------------------------------
extern "C" void kernel_launch(void* const* d_in, const int* in_sizes, int n_in,
                              void* d_out, int out_size, void* d_ws,
                              size_t ws_size, hipStream_t stream)
{
    const float* s      = (const float*)d_in[0];
    const float* a_prev = (const float*)d_in[1];
    const float* r_prev = (const float*)d_in[2];
    const float* h      = (const float*)d_in[3];
    const float* c      = (const float*)d_in[4];
    const float* Wx     = (const float*)d_in[5];
    const float* Wh     = (const float*)d_in[6];
    const float* bh     = (const float*)d_in[7];
    const float* Wa     = (const float*)d_in[8];
    const float* ba     = (const float*)d_in[9];
    const float* Wv     = (const float*)d_in[10];
    const float* bv     = (const float*)d_in[11];

    float* out   = (float*)d_out;
    float* probs = out;                        // [4096*64]
    float* vout  = out + (size_t)BATCH * ADIM; // [4096]

    // Workspace layout (16B-aligned)
    char* ws = (char*)d_ws;
    __hip_bfloat16* xb   = (__hip_bfloat16*)ws;                 //  5,242,880
    __hip_bfloat16* wxt  = (__hip_bfloat16*)(ws + 5242880);     // 10,485,760
    __hip_bfloat16* waT  = (__hip_bfloat16*)(ws + 15728640);    //    262,144
    float* zh_w          = (float*)(ws + 15990784);             //    262,144
    __hip_bfloat16* hnew = (__hip_bfloat16*)(ws + 16252928);    // 16,777,216
    // total 33,030,144 bytes

    setup_kernel<<<7040, 256, 0, stream>>>(
        s, a_prev, r_prev, h, Wx, Wh, Wa, xb, wxt, waT, zh_w);
    lstm_gemm<<<dim3(BATCH / 128, HDIM / 32), 256, 0, stream>>>(
        xb, wxt, zh_w, bh, c, hnew);
    head_kernel<<<BATCH / 16, 512, 0, stream>>>(
        hnew, waT, Wv, ba, bv, probs, vout);
}

// Round 6
// 220.712 us; speedup vs baseline: 1.3033x; 1.0497x over previous
//
#include <hip/hip_runtime.h>
#include <hip/hip_bf16.h>

// Problem constants
#define BATCH   4096
#define SDIM    512
#define ADIM    64
#define IDIM    577           // 512 + 64 + 1
#define KP2     640           // IDIM padded to 20*32
#define NKT     20            // K-tiles of 32
#define HDIM    2048
#define ZDIM    8192          // 4*HDIM
#define BUFE    (128 * 32)    // LDS elems per buffer (8KB)

typedef __attribute__((ext_vector_type(8))) __bf16 bf16x8;
typedef __attribute__((ext_vector_type(4))) float  accx4;

// ---------------------------------------------------------------------------
// Fused setup kernel. Role by flat blockIdx (all independent):
//   [0,1280)     transpose Wx: 64k x 64n tiles -> wxt [8192][640]bf16
//   [1280,1536)  zh partials: zh_w[ky][n] = sum_{k in ky*256..+256} h*Wh
//   [1536,5632)  prep xb rows: bf16 [s|a|r|0pad] (4096 x 640)
//   [5632,5760)  transpose Wa [2048,64]f32 -> waT [64][2048]bf16
// ---------------------------------------------------------------------------
__global__ __launch_bounds__(256) void setup_kernel(
    const float* __restrict__ s, const float* __restrict__ a_prev,
    const float* __restrict__ r_prev, const float* __restrict__ h,
    const float* __restrict__ wx, const float* __restrict__ wh,
    const float* __restrict__ wa,
    __hip_bfloat16* __restrict__ xb, __hip_bfloat16* __restrict__ wxt,
    __hip_bfloat16* __restrict__ waT, float* __restrict__ zh_w)
{
    __shared__ float stile[64 * 65];        // 16.6KB, stride 65 (conflict-free)
    const int bid = blockIdx.x;
    const int t = threadIdx.x;

    if (bid < 1280) {                       // ---- transpose Wx (64k x 64n)
        const int kt2 = bid >> 7;           // 0..9
        const int nt  = bid & 127;          // 0..127
        const int c4  = t & 15;             // float4 column
        const int rr  = t >> 4;             // 0..15
#pragma unroll
        for (int i = 0; i < 4; ++i) {
            const int r = rr + i * 16;      // k within tile
            const int k = kt2 * 64 + r;
            float4 v = (k < IDIM)
                ? *(const float4*)(wx + (size_t)k * ZDIM + nt * 64 + c4 * 4)
                : float4{0.f, 0.f, 0.f, 0.f};
            *(float4*)(stile + r * 65 + c4 * 4) = v;
        }
        __syncthreads();
        const int ch = t & 7;               // k-chunk
#pragma unroll
        for (int i = 0; i < 2; ++i) {
            const int nr = (t >> 3) + i * 32;   // n-row 0..63
            bf16x8 w8;
#pragma unroll
            for (int j = 0; j < 8; ++j)
                w8[j] = (__bf16)stile[(ch * 8 + j) * 65 + nr];
            *(bf16x8*)(wxt + (size_t)(nt * 64 + nr) * KP2 + kt2 * 64 + ch * 8)
                = w8;
        }
    } else if (bid < 1536) {                // ---- zh partials (8 k-splits)
        const int zb = bid - 1280;
        const int nb = zb & 31, ky = zb >> 5;       // nb 0..31, ky 0..7
        const int n  = nb * 256 + t;
        const float* hp  = h + ky * 256;
        const float* whp = wh + (size_t)ky * 256 * ZDIM + n;
        float p = 0.0f;
#pragma unroll 16
        for (int kk = 0; kk < 256; ++kk)
            p = fmaf(hp[kk], whp[(size_t)kk * ZDIM], p);
        zh_w[ky * ZDIM + n] = p;
    } else if (bid < 5632) {                // ---- prep xb row
        const int row = bid - 1536;
        const float* srow = s + (size_t)row * SDIM;
        const float* arow = a_prev + (size_t)row * ADIM;
        __hip_bfloat16* xrow = xb + (size_t)row * KP2;
        for (int c = t; c < KP2; c += 256) {
            float v;
            if (c < SDIM)        v = srow[c];
            else if (c < 576)    v = arow[c - SDIM];
            else if (c == 576)   v = r_prev[row];
            else                 v = 0.0f;
            xrow[c] = __float2bfloat16(v);
        }
    } else {                                // ---- transpose Wa (32k x 32a)
        const int wb = bid - 5632;
        const int kt = wb >> 1, at = wb & 1;
        const int c  = t & 31, r0 = t >> 5;
#pragma unroll
        for (int i = 0; i < 4; ++i) {
            int r = r0 + i * 8;             // k within tile
            stile[r * 33 + c] = wa[(size_t)(kt * 32 + r) * ADIM + at * 32 + c];
        }
        __syncthreads();
#pragma unroll
        for (int i = 0; i < 4; ++i) {
            int r = r0 + i * 8;             // action within tile
            waT[(size_t)(at * 32 + r) * HDIM + kt * 32 + c] =
                __float2bfloat16(stile[c * 33 + r]);
        }
    }
}

// ---------------------------------------------------------------------------
// zh_reduce: zh[j] = bh[j] + sum_p zh_w[p][j]   (8192 elems, 32 blocks)
// ---------------------------------------------------------------------------
__global__ __launch_bounds__(256) void zh_reduce(
    const float* __restrict__ zh_w, const float* __restrict__ bh,
    float* __restrict__ zh)
{
    const int j = blockIdx.x * 256 + threadIdx.x;
    float v = bh[j];
#pragma unroll
    for (int p = 0; p < 8; ++p)
        v += zh_w[p * ZDIM + j];
    zh[j] = v;
}

// ---------------------------------------------------------------------------
// Main bf16 MFMA GEMM + fused LSTM epilogue — DOUBLE-BUFFERED LDS, BK=32.
// Block tile: 128 rows x 32 h-units (128 z-cols over 4 gates).
// 32KB LDS total + launch_bounds(256,3) -> 3 blocks/CU (12 waves): more
// co-resident waves to hide the per-barrier vmcnt(0) drain (R5: only ~1.6
// blocks/CU at 64KB was the limiter). 16B chunks XOR-swizzled with
// chunk ^ (r&3) ^ ((r>>2)&3): staging stays lane-contiguous, fragment
// reads alias <=2-way (free, m136).
// ---------------------------------------------------------------------------
__device__ __forceinline__ float sigmoid_f(float x) {
    return 1.0f / (1.0f + __expf(-x));
}
__device__ __forceinline__ float tanh_f(float x) {
    return 1.0f - 2.0f / (1.0f + __expf(2.0f * x));
}

__global__ __launch_bounds__(256, 3) void lstm_gemm(
    const __hip_bfloat16* __restrict__ xb,   // [4096][640] bf16
    const __hip_bfloat16* __restrict__ wxt,  // [8192][640] bf16 (n-major)
    const float* __restrict__ zh,            // [8192] final bias+h@Wh
    const float* __restrict__ cvec,          // [2048]
    __hip_bfloat16* __restrict__ hout)       // [4096][2048] bf16
{
    __shared__ __bf16 smA[2 * BUFE];   // 16KB  [buf][row][chunk swizzled]
    __shared__ __bf16 smB[2 * BUFE];   // 16KB  [buf][zcol][chunk swizzled]
    const int t    = threadIdx.x;
    const int lane = t & 63;
    const int wid  = t >> 6;
    const int m0   = blockIdx.x * 128;
    const int n0   = blockIdx.y * 32;
    const int wm   = wid >> 1, wn = wid & 1;
    const int fl15 = lane & 15;
    const int fhi  = lane >> 4;        // 0..3

    accx4 acc[4][4] = {};              // [gate][rowtile]

    // ---- staging addresses: lane -> (srow = lane>>2, slot = lane&3).
    // Stored chunk at (row, slot) is slot ^ (row&3) ^ ((row>>2)&3); for the
    // lane-contiguous dest this reduces to a lane-constant source chunk:
    const int cch = (lane & 3) ^ ((lane >> 2) & 3) ^ ((lane >> 4) & 3);
    const __bf16* gA[2]; const __bf16* gB[2]; int lofs[2];
#pragma unroll
    for (int i = 0; i < 2; ++i) {
        const int rbase = wid * 32 + i * 16;
        const int r = rbase + (lane >> 2);                   // 0..127
        gA[i] = (const __bf16*)xb + (size_t)(m0 + r) * KP2 + cch * 8;
        const int g = r >> 5, nn = r & 31;
        gB[i] = (const __bf16*)wxt +
                (size_t)(g * HDIM + n0 + nn) * KP2 + cch * 8;
        lofs[i] = rbase * 32;                                // wave-uniform
    }

    auto stage = [&](int tile, int p) {
        const int ko = tile * 32;
        const int po = p * BUFE;
#pragma unroll
        for (int i = 0; i < 2; ++i) {
            __builtin_amdgcn_global_load_lds(
                (const __attribute__((address_space(1))) void*)(gA[i] + ko),
                (__attribute__((address_space(3))) void*)(smA + po + lofs[i]),
                16, 0, 0);
            __builtin_amdgcn_global_load_lds(
                (const __attribute__((address_space(1))) void*)(gB[i] + ko),
                (__attribute__((address_space(3))) void*)(smB + po + lofs[i]),
                16, 0, 0);
        }
    };

    // de-swizzle slot for fragment reads (row = fl15 within any 16-row tile;
    // tile bases are multiples of 16 so only fl15 enters the XOR):
    const int sl = ((fhi ^ (fl15 & 3) ^ ((fl15 >> 2) & 3)) * 8);

    auto compute = [&](int p) {
        const int po = p * BUFE;
        bf16x8 af[4], bfr[4];
#pragma unroll
        for (int rt = 0; rt < 4; ++rt)
            af[rt] = *(const bf16x8*)(smA + po +
                (wm * 64 + rt * 16 + fl15) * 32 + sl);
#pragma unroll
        for (int g = 0; g < 4; ++g)
            bfr[g] = *(const bf16x8*)(smB + po +
                (g * 32 + wn * 16 + fl15) * 32 + sl);
#pragma unroll
        for (int g = 0; g < 4; ++g)
#pragma unroll
            for (int rt = 0; rt < 4; ++rt)
                acc[g][rt] = __builtin_amdgcn_mfma_f32_16x16x32_bf16(
                    af[rt], bfr[g], acc[g][rt], 0, 0, 0);
    };

    stage(0, 0);
    __syncthreads();                   // tile 0 landed
#pragma unroll
    for (int kt = 0; kt < NKT - 1; ++kt) {
        stage(kt + 1, (kt + 1) & 1);   // issue next tile FIRST
        compute(kt & 1);               // overlap latency with MFMAs
        __syncthreads();
    }
    compute((NKT - 1) & 1);            // last tile, no barrier needed

    // Epilogue. C/D layout: col=lane&15, row=(lane>>4)*4+reg (m89/m91).
    const int colg = n0 + wn * 16 + fl15;        // h-unit index
    const float zhi = zh[colg];
    const float zhf = zh[HDIM + colg];
    const float zhg = zh[2 * HDIM + colg];
    const float zho = zh[3 * HDIM + colg];
    const float cv  = cvec[colg];
#pragma unroll
    for (int rt = 0; rt < 4; ++rt) {
#pragma unroll
        for (int r = 0; r < 4; ++r) {
            const int row = m0 + wm * 64 + rt * 16 + (fhi << 2) + r;
            const float zi = acc[0][rt][r] + zhi;
            const float zf = acc[1][rt][r] + zhf;
            const float zg = acc[2][rt][r] + zhg;
            const float zo = acc[3][rt][r] + zho;
            const float cn = sigmoid_f(zf) * cv + sigmoid_f(zi) * tanh_f(zg);
            const float hn = sigmoid_f(zo) * tanh_f(cn);
            hout[(size_t)row * HDIM + colg] = __float2bfloat16(hn);
        }
    }
}

// ---------------------------------------------------------------------------
// Policy+value head: logits = hnew@Wa + ba (MFMA, K split over 2 wave-groups,
// dual accumulators), fused softmax; v = hnew@Wv + bv (fp32 Wv, 4 indep
// accumulator chains — R5's single chain was 256 serial fmaf deep).
// 512 threads: wave = (kh = wid>>2, action-tile = wid&3). Block = 16 rows.
// ---------------------------------------------------------------------------
__global__ __launch_bounds__(512) void head_kernel(
    const __hip_bfloat16* __restrict__ hnew,  // [4096][2048] bf16
    const __hip_bfloat16* __restrict__ waT,   // [64][2048] bf16
    const float* __restrict__ wv,             // [2048] f32
    const float* __restrict__ ba, const float* __restrict__ bv,
    float* __restrict__ probs, float* __restrict__ vout)
{
    __shared__ float lg[2][16][68];
    __shared__ float vpart[2][16];
    const int t    = threadIdx.x;
    const int lane = t & 63;
    const int wid  = t >> 6;           // 0..7
    const int kh   = wid >> 2;         // k half
    const int wid2 = wid & 3;          // action tile
    const int r0   = blockIdx.x * 16;
    const int fl15 = lane & 15, fhi = lane >> 4;

    const __bf16* arow = (const __bf16*)hnew +
        (size_t)(r0 + fl15) * HDIM + kh * 1024 + fhi * 8;
    const __bf16* brow = (const __bf16*)waT +
        (size_t)(wid2 * 16 + fl15) * HDIM + kh * 1024 + fhi * 8;
    const float* wvp = wv + kh * 1024 + fhi * 8;
    const bool do_v = (wid2 == 0);

    accx4 acc0 = {}, acc1 = {};
    float va0 = 0.f, va1 = 0.f, va2 = 0.f, va3 = 0.f;
#pragma unroll 4
    for (int kk = 0; kk < 1024; kk += 64) {
        bf16x8 a0 = *(const bf16x8*)(arow + kk);
        bf16x8 b0 = *(const bf16x8*)(brow + kk);
        bf16x8 a1 = *(const bf16x8*)(arow + kk + 32);
        bf16x8 b1 = *(const bf16x8*)(brow + kk + 32);
        acc0 = __builtin_amdgcn_mfma_f32_16x16x32_bf16(a0, b0, acc0, 0, 0, 0);
        acc1 = __builtin_amdgcn_mfma_f32_16x16x32_bf16(a1, b1, acc1, 0, 0, 0);
        if (do_v) {
#pragma unroll
            for (int j = 0; j < 8; j += 4) {
                va0 = fmaf((float)a0[j],     wvp[kk + j],          va0);
                va1 = fmaf((float)a0[j + 1], wvp[kk + j + 1],      va1);
                va2 = fmaf((float)a0[j + 2], wvp[kk + j + 2],      va2);
                va3 = fmaf((float)a0[j + 3], wvp[kk + j + 3],      va3);
                va0 = fmaf((float)a1[j],     wvp[kk + 32 + j],     va0);
                va1 = fmaf((float)a1[j + 1], wvp[kk + 32 + j + 1], va1);
                va2 = fmaf((float)a1[j + 2], wvp[kk + 32 + j + 2], va2);
                va3 = fmaf((float)a1[j + 3], wvp[kk + 32 + j + 3], va3);
            }
        }
    }
    // C/D layout: col(action-in-tile)=lane&15, row=(lane>>4)*4+reg
#pragma unroll
    for (int r = 0; r < 4; ++r)
        lg[kh][fhi * 4 + r][wid2 * 16 + fl15] = acc0[r] + acc1[r];
    if (do_v) {
        float vacc = (va0 + va1) + (va2 + va3);
        vacc += __shfl_xor(vacc, 16);
        vacc += __shfl_xor(vacc, 32);
        if (lane < 16) vpart[kh][lane] = vacc;
    }
    __syncthreads();

    // softmax: 8 waves x 2 rows; lane = action (wave width 64 = ADIM)
    const float bav = ba[lane];
#pragma unroll
    for (int i = 0; i < 2; ++i) {
        const int row = wid * 2 + i;
        const float logit = lg[0][row][lane] + lg[1][row][lane] + bav;
        float m = logit;
#pragma unroll
        for (int mask = 32; mask >= 1; mask >>= 1)
            m = fmaxf(m, __shfl_xor(m, mask));
        const float e = __expf(logit - m);
        float ssum = e;
#pragma unroll
        for (int mask = 32; mask >= 1; mask >>= 1)
            ssum += __shfl_xor(ssum, mask);
        probs[(size_t)(r0 + row) * 64 + lane] = e / ssum;
    }
    if (t < 16) vout[r0 + t] = vpart[0][t] + vpart[1][t] + bv[0];
}

// ---------------------------------------------------------------------------
extern "C" void kernel_launch(void* const* d_in, const int* in_sizes, int n_in,
                              void* d_out, int out_size, void* d_ws,
                              size_t ws_size, hipStream_t stream)
{
    const float* s      = (const float*)d_in[0];
    const float* a_prev = (const float*)d_in[1];
    const float* r_prev = (const float*)d_in[2];
    const float* h      = (const float*)d_in[3];
    const float* c      = (const float*)d_in[4];
    const float* Wx     = (const float*)d_in[5];
    const float* Wh     = (const float*)d_in[6];
    const float* bh     = (const float*)d_in[7];
    const float* Wa     = (const float*)d_in[8];
    const float* ba     = (const float*)d_in[9];
    const float* Wv     = (const float*)d_in[10];
    const float* bv     = (const float*)d_in[11];

    float* out   = (float*)d_out;
    float* probs = out;                        // [4096*64]
    float* vout  = out + (size_t)BATCH * ADIM; // [4096]

    // Workspace layout (16B-aligned)
    char* ws = (char*)d_ws;
    __hip_bfloat16* xb   = (__hip_bfloat16*)ws;                 //  5,242,880
    __hip_bfloat16* wxt  = (__hip_bfloat16*)(ws + 5242880);     // 10,485,760
    __hip_bfloat16* waT  = (__hip_bfloat16*)(ws + 15728640);    //    262,144
    float* zh_w          = (float*)(ws + 15990784);             //    262,144
    float* zh            = (float*)(ws + 16252928);             //     32,768
    __hip_bfloat16* hnew = (__hip_bfloat16*)(ws + 16285696);    // 16,777,216
    // total 33,062,912 bytes

    setup_kernel<<<5760, 256, 0, stream>>>(
        s, a_prev, r_prev, h, Wx, Wh, Wa, xb, wxt, waT, zh_w);
    zh_reduce<<<ZDIM / 256, 256, 0, stream>>>(zh_w, bh, zh);
    lstm_gemm<<<dim3(BATCH / 128, HDIM / 32), 256, 0, stream>>>(
        xb, wxt, zh, c, hnew);
    head_kernel<<<BATCH / 16, 512, 0, stream>>>(
        hnew, waT, Wv, ba, bv, probs, vout);
}

// Round 7
// 213.242 us; speedup vs baseline: 1.3490x; 1.0350x over previous
//
#include <hip/hip_runtime.h>
#include <hip/hip_bf16.h>

// Problem constants
#define BATCH   4096
#define SDIM    512
#define ADIM    64
#define IDIM    577           // 512 + 64 + 1
#define KP2     640           // IDIM padded to 10*64
#define NKT64   10            // K-tiles of 64
#define HDIM    2048
#define ZDIM    8192          // 4*HDIM
#define BUFE    (128 * 64)    // LDS elems per buffer (16KB)

typedef __attribute__((ext_vector_type(8))) __bf16 bf16x8;
typedef __attribute__((ext_vector_type(4))) float  accx4;

// ---------------------------------------------------------------------------
// Fused setup kernel. Role by flat blockIdx (all independent):
//   [0,1280)     transpose Wx: 64k x 64n tiles -> wxt [8192][640]bf16
//   [1280,1536)  zh partials: zh_w[ky][n] = sum_{k in ky*256..+256} h*Wh
//   [1536,5632)  prep xb rows: bf16 [s|a|r|0pad] (4096 x 640)
//   [5632,5760)  transpose Wa [2048,64]f32 -> waT [64][2048]bf16
// ---------------------------------------------------------------------------
__global__ __launch_bounds__(256) void setup_kernel(
    const float* __restrict__ s, const float* __restrict__ a_prev,
    const float* __restrict__ r_prev, const float* __restrict__ h,
    const float* __restrict__ wx, const float* __restrict__ wh,
    const float* __restrict__ wa,
    __hip_bfloat16* __restrict__ xb, __hip_bfloat16* __restrict__ wxt,
    __hip_bfloat16* __restrict__ waT, float* __restrict__ zh_w)
{
    __shared__ float stile[64 * 65];        // 16.6KB, stride 65 (conflict-free)
    const int bid = blockIdx.x;
    const int t = threadIdx.x;

    if (bid < 1280) {                       // ---- transpose Wx (64k x 64n)
        const int kt2 = bid >> 7;           // 0..9
        const int nt  = bid & 127;          // 0..127
        const int c4  = t & 15;             // float4 column
        const int rr  = t >> 4;             // 0..15
#pragma unroll
        for (int i = 0; i < 4; ++i) {
            const int r = rr + i * 16;      // k within tile
            const int k = kt2 * 64 + r;
            float4 v = (k < IDIM)
                ? *(const float4*)(wx + (size_t)k * ZDIM + nt * 64 + c4 * 4)
                : float4{0.f, 0.f, 0.f, 0.f};
            *(float4*)(stile + r * 65 + c4 * 4) = v;
        }
        __syncthreads();
        const int ch = t & 7;               // k-chunk
#pragma unroll
        for (int i = 0; i < 2; ++i) {
            const int nr = (t >> 3) + i * 32;   // n-row 0..63
            bf16x8 w8;
#pragma unroll
            for (int j = 0; j < 8; ++j)
                w8[j] = (__bf16)stile[(ch * 8 + j) * 65 + nr];
            *(bf16x8*)(wxt + (size_t)(nt * 64 + nr) * KP2 + kt2 * 64 + ch * 8)
                = w8;
        }
    } else if (bid < 1536) {                // ---- zh partials (8 k-splits)
        const int zb = bid - 1280;
        const int nb = zb & 31, ky = zb >> 5;       // nb 0..31, ky 0..7
        const int n  = nb * 256 + t;
        const float* hp  = h + ky * 256;
        const float* whp = wh + (size_t)ky * 256 * ZDIM + n;
        float p = 0.0f;
#pragma unroll 16
        for (int kk = 0; kk < 256; ++kk)
            p = fmaf(hp[kk], whp[(size_t)kk * ZDIM], p);
        zh_w[ky * ZDIM + n] = p;
    } else if (bid < 5632) {                // ---- prep xb row
        const int row = bid - 1536;
        const float* srow = s + (size_t)row * SDIM;
        const float* arow = a_prev + (size_t)row * ADIM;
        __hip_bfloat16* xrow = xb + (size_t)row * KP2;
        for (int c = t; c < KP2; c += 256) {
            float v;
            if (c < SDIM)        v = srow[c];
            else if (c < 576)    v = arow[c - SDIM];
            else if (c == 576)   v = r_prev[row];
            else                 v = 0.0f;
            xrow[c] = __float2bfloat16(v);
        }
    } else {                                // ---- transpose Wa (32k x 32a)
        const int wb = bid - 5632;
        const int kt = wb >> 1, at = wb & 1;
        const int c  = t & 31, r0 = t >> 5;
#pragma unroll
        for (int i = 0; i < 4; ++i) {
            int r = r0 + i * 8;             // k within tile
            stile[r * 33 + c] = wa[(size_t)(kt * 32 + r) * ADIM + at * 32 + c];
        }
        __syncthreads();
#pragma unroll
        for (int i = 0; i < 4; ++i) {
            int r = r0 + i * 8;             // action within tile
            waT[(size_t)(at * 32 + r) * HDIM + kt * 32 + c] =
                __float2bfloat16(stile[c * 33 + r]);
        }
    }
}

// ---------------------------------------------------------------------------
// zh_reduce: zh[j] = bh[j] + sum_p zh_w[p][j]   (8192 elems, 32 blocks)
// ---------------------------------------------------------------------------
__global__ __launch_bounds__(256) void zh_reduce(
    const float* __restrict__ zh_w, const float* __restrict__ bh,
    float* __restrict__ zh)
{
    const int j = blockIdx.x * 256 + threadIdx.x;
    float v = bh[j];
#pragma unroll
    for (int p = 0; p < 8; ++p)
        v += zh_w[p * ZDIM + j];
    zh[j] = v;
}

// ---------------------------------------------------------------------------
// Main bf16 MFMA GEMM + fused LSTM epilogue — R5-proven config:
// BK=64, double-buffered LDS (64KB), 128B LDS rows, slot = chunk ^ (row&7)
// swizzle (HW-verified 0 conflicts in R3/R5; the R6 64B-row 4-bit XOR
// measured 5.2M conflicts — do not regress to it).
// Block tile: 128 rows x 32 h-units (128 z-cols over 4 gates).
// ---------------------------------------------------------------------------
__device__ __forceinline__ float sigmoid_f(float x) {
    return 1.0f / (1.0f + __expf(-x));
}
__device__ __forceinline__ float tanh_f(float x) {
    return 1.0f - 2.0f / (1.0f + __expf(2.0f * x));
}

__global__ __launch_bounds__(256, 2) void lstm_gemm(
    const __hip_bfloat16* __restrict__ xb,   // [4096][640] bf16
    const __hip_bfloat16* __restrict__ wxt,  // [8192][640] bf16 (n-major)
    const float* __restrict__ zh,            // [8192] final bias + h@Wh
    const float* __restrict__ cvec,          // [2048]
    __hip_bfloat16* __restrict__ hout)       // [4096][2048] bf16
{
    __shared__ __bf16 smA[2 * BUFE];   // 32KB  [buf][row][k-chunk swizzled]
    __shared__ __bf16 smB[2 * BUFE];   // 32KB  [buf][zcol][k-chunk swizzled]
    const int t    = threadIdx.x;
    const int lane = t & 63;
    const int wid  = t >> 6;
    const int m0   = blockIdx.x * 128;
    const int n0   = blockIdx.y * 32;
    const int wm   = wid >> 1, wn = wid & 1;
    const int fl15 = lane & 15;
    const int fhi  = lane >> 4;        // 0..3

    accx4 acc[4][4] = {};              // [gate][rowtile]

    // ---- staging addresses (loop-invariant) ----
    const int srow = lane >> 3;        // 0..7
    const int slot = lane & 7;
    const int cch  = slot ^ srow;      // swizzled source chunk (lane-const)
    const __bf16* gA[4]; const __bf16* gB[4]; int lofs[4];
#pragma unroll
    for (int i = 0; i < 4; ++i) {
        const int r = wid * 32 + i * 8 + srow;               // 0..127
        gA[i] = (const __bf16*)xb + (size_t)(m0 + r) * KP2 + cch * 8;
        const int g = r >> 5, nn = r & 31;
        gB[i] = (const __bf16*)wxt +
                (size_t)(g * HDIM + n0 + nn) * KP2 + cch * 8;
        lofs[i] = (wid * 32 + i * 8) * 64;                   // wave-uniform
    }

    auto stage = [&](int tile, int p) {
        const int ko = tile * 64;
        const int po = p * BUFE;
#pragma unroll
        for (int i = 0; i < 4; ++i) {
            __builtin_amdgcn_global_load_lds(
                (const __attribute__((address_space(1))) void*)(gA[i] + ko),
                (__attribute__((address_space(3))) void*)(smA + po + lofs[i]),
                16, 0, 0);
            __builtin_amdgcn_global_load_lds(
                (const __attribute__((address_space(1))) void*)(gB[i] + ko),
                (__attribute__((address_space(3))) void*)(smB + po + lofs[i]),
                16, 0, 0);
        }
    };

    auto compute = [&](int p) {
        const int po = p * BUFE;
#pragma unroll
        for (int hf = 0; hf < 2; ++hf) {
            const int ck = hf * 4 + fhi;                     // wanted chunk
            const int sl = (ck ^ (fl15 & 7)) * 8;            // de-swizzle
            bf16x8 af[4], bfr[4];
#pragma unroll
            for (int rt = 0; rt < 4; ++rt)
                af[rt] = *(const bf16x8*)(smA + po +
                    (wm * 64 + rt * 16 + fl15) * 64 + sl);
#pragma unroll
            for (int g = 0; g < 4; ++g)
                bfr[g] = *(const bf16x8*)(smB + po +
                    (g * 32 + wn * 16 + fl15) * 64 + sl);
#pragma unroll
            for (int g = 0; g < 4; ++g)
#pragma unroll
                for (int rt = 0; rt < 4; ++rt)
                    acc[g][rt] = __builtin_amdgcn_mfma_f32_16x16x32_bf16(
                        af[rt], bfr[g], acc[g][rt], 0, 0, 0);
        }
    };

    stage(0, 0);
    __syncthreads();                   // tile 0 landed
#pragma unroll
    for (int kt = 0; kt < NKT64 - 1; ++kt) {
        stage(kt + 1, (kt + 1) & 1);   // issue next tile FIRST
        compute(kt & 1);               // overlap latency with MFMAs
        __syncthreads();
    }
    compute((NKT64 - 1) & 1);          // last tile, no barrier needed

    // Epilogue. C/D layout: col=lane&15, row=(lane>>4)*4+reg (m89/m91).
    const int colg = n0 + wn * 16 + fl15;        // h-unit index
    const float zhi = zh[colg];
    const float zhf = zh[HDIM + colg];
    const float zhg = zh[2 * HDIM + colg];
    const float zho = zh[3 * HDIM + colg];
    const float cv  = cvec[colg];
#pragma unroll
    for (int rt = 0; rt < 4; ++rt) {
#pragma unroll
        for (int r = 0; r < 4; ++r) {
            const int row = m0 + wm * 64 + rt * 16 + (fhi << 2) + r;
            const float zi = acc[0][rt][r] + zhi;
            const float zf = acc[1][rt][r] + zhf;
            const float zg = acc[2][rt][r] + zhg;
            const float zo = acc[3][rt][r] + zho;
            const float cn = sigmoid_f(zf) * cv + sigmoid_f(zi) * tanh_f(zg);
            const float hn = sigmoid_f(zo) * tanh_f(cn);
            hout[(size_t)row * HDIM + colg] = __float2bfloat16(hn);
        }
    }
}

// ---------------------------------------------------------------------------
// Policy+value head v3. Block = 16 rows, 512 threads, 8 waves.
// Wave w owns K-eighth [w*256, w*256+256): per k-step ONE A-frag feeds all
// 4 action-tiles (4 independent acc chains of depth 8) + fused v-partials.
// hnew is read exactly once device-wide (16.8 MB); waT is L2-hot.
// Partial logits summed via LDS, then per-wave softmax (lane = action).
// ---------------------------------------------------------------------------
__global__ __launch_bounds__(512) void head_kernel(
    const __hip_bfloat16* __restrict__ hnew,  // [4096][2048] bf16
    const __hip_bfloat16* __restrict__ waT,   // [64][2048] bf16
    const float* __restrict__ wv,             // [2048] f32
    const float* __restrict__ ba, const float* __restrict__ bv,
    float* __restrict__ probs, float* __restrict__ vout)
{
    __shared__ float lg[8][16][68];    // 34.8KB partial logits
    __shared__ float vpart[8][16];
    const int t    = threadIdx.x;
    const int lane = t & 63;
    const int w    = t >> 6;           // k-eighth 0..7
    const int r0   = blockIdx.x * 16;
    const int fl15 = lane & 15, fhi = lane >> 4;
    const int k0   = w * 256;

    const __bf16* arow = (const __bf16*)hnew +
        (size_t)(r0 + fl15) * HDIM + k0 + fhi * 8;
    const __bf16* brow = (const __bf16*)waT +
        (size_t)fl15 * HDIM + k0 + fhi * 8;
    const float* wvp = wv + k0 + fhi * 8;

    accx4 acc[4] = {};
    float va0 = 0.f, va1 = 0.f;
#pragma unroll
    for (int kk = 0; kk < 256; kk += 32) {
        bf16x8 af = *(const bf16x8*)(arow + kk);
#pragma unroll
        for (int a = 0; a < 4; ++a) {
            bf16x8 bf = *(const bf16x8*)(brow + (size_t)a * 16 * HDIM + kk);
            acc[a] = __builtin_amdgcn_mfma_f32_16x16x32_bf16(
                af, bf, acc[a], 0, 0, 0);
        }
#pragma unroll
        for (int j = 0; j < 4; ++j) {
            va0 = fmaf((float)af[j],     wvp[kk + j],     va0);
            va1 = fmaf((float)af[j + 4], wvp[kk + j + 4], va1);
        }
    }
    // C/D layout: col(action-in-tile)=lane&15, row=(lane>>4)*4+reg
#pragma unroll
    for (int a = 0; a < 4; ++a)
#pragma unroll
        for (int r = 0; r < 4; ++r)
            lg[w][fhi * 4 + r][a * 16 + fl15] = acc[a][r];
    // v partial for row fl15 over this wave's k-chunks: reduce across fhi
    float va = va0 + va1;
    va += __shfl_xor(va, 16);
    va += __shfl_xor(va, 32);
    if (lane < 16) vpart[w][lane] = va;
    __syncthreads();

    // softmax: wave w owns rows 2w, 2w+1; lane = action (wave width = 64)
    const float bav = ba[lane];
#pragma unroll
    for (int i = 0; i < 2; ++i) {
        const int row = w * 2 + i;
        float logit = bav;
#pragma unroll
        for (int p = 0; p < 8; ++p)
            logit += lg[p][row][lane];
        float m = logit;
#pragma unroll
        for (int mask = 32; mask >= 1; mask >>= 1)
            m = fmaxf(m, __shfl_xor(m, mask));
        const float e = __expf(logit - m);
        float ssum = e;
#pragma unroll
        for (int mask = 32; mask >= 1; mask >>= 1)
            ssum += __shfl_xor(ssum, mask);
        probs[(size_t)(r0 + row) * 64 + lane] = e / ssum;
    }
    if (t < 16) {
        float v = bv[0];
#pragma unroll
        for (int p = 0; p < 8; ++p)
            v += vpart[p][t];
        vout[r0 + t] = v;
    }
}

// ---------------------------------------------------------------------------
extern "C" void kernel_launch(void* const* d_in, const int* in_sizes, int n_in,
                              void* d_out, int out_size, void* d_ws,
                              size_t ws_size, hipStream_t stream)
{
    const float* s      = (const float*)d_in[0];
    const float* a_prev = (const float*)d_in[1];
    const float* r_prev = (const float*)d_in[2];
    const float* h      = (const float*)d_in[3];
    const float* c      = (const float*)d_in[4];
    const float* Wx     = (const float*)d_in[5];
    const float* Wh     = (const float*)d_in[6];
    const float* bh     = (const float*)d_in[7];
    const float* Wa     = (const float*)d_in[8];
    const float* ba     = (const float*)d_in[9];
    const float* Wv     = (const float*)d_in[10];
    const float* bv     = (const float*)d_in[11];

    float* out   = (float*)d_out;
    float* probs = out;                        // [4096*64]
    float* vout  = out + (size_t)BATCH * ADIM; // [4096]

    // Workspace layout (16B-aligned)
    char* ws = (char*)d_ws;
    __hip_bfloat16* xb   = (__hip_bfloat16*)ws;                 //  5,242,880
    __hip_bfloat16* wxt  = (__hip_bfloat16*)(ws + 5242880);     // 10,485,760
    __hip_bfloat16* waT  = (__hip_bfloat16*)(ws + 15728640);    //    262,144
    float* zh_w          = (float*)(ws + 15990784);             //    262,144
    float* zh            = (float*)(ws + 16252928);             //     32,768
    __hip_bfloat16* hnew = (__hip_bfloat16*)(ws + 16285696);    // 16,777,216
    // total 33,062,912 bytes

    setup_kernel<<<5760, 256, 0, stream>>>(
        s, a_prev, r_prev, h, Wx, Wh, Wa, xb, wxt, waT, zh_w);
    zh_reduce<<<ZDIM / 256, 256, 0, stream>>>(zh_w, bh, zh);
    lstm_gemm<<<dim3(BATCH / 128, HDIM / 32), 256, 0, stream>>>(
        xb, wxt, zh, c, hnew);
    head_kernel<<<BATCH / 16, 512, 0, stream>>>(
        hnew, waT, Wv, ba, bv, probs, vout);
}